// Round 15
// baseline (403.066 us; speedup 1.0000x reference)
//
#include <hip/hip_runtime.h>

#define D 128
#define NB 250    // node buckets
#define BN 200    // nodes per bucket (NB*BN == n == 50000)
#define NBLK 512  // histogram/partition blocks (power of 2)
#define CAP 7168  // LDS-staged edges per bucket; global-read fallback past this
#define NT 4      // feature tiles (32 feats = one 64B line per row per tile)

typedef float f2v __attribute__((ext_vector_type(2)));
typedef short bf16x8 __attribute__((ext_vector_type(8)));
typedef float f32x4 __attribute__((ext_vector_type(4)));

// bf16 round-to-nearest-even
__device__ __forceinline__ unsigned bf16r(float f) {
  unsigned u = __float_as_uint(f);
  return (u + 0x7fffu + ((u >> 16) & 1u)) >> 16;
}

// ---------------- pass A + converts ----------------
// blocks [0,NBLK): LDS bucket histogram of dst -> M[bkt][blk] (transposed)
// blocks [NBLK,NBLK+GC): x -> bf16 ; rest: W -> bf16 transposed [n][k]

__global__ __launch_bounds__(256) void k_pre1(const int* __restrict__ dst, int* __restrict__ M, int E,
                                              const float* __restrict__ X, unsigned short* __restrict__ Xb,
                                              int total4, int GC,
                                              const float* __restrict__ W0, const float* __restrict__ W1,
                                              const float* __restrict__ W2, unsigned short* __restrict__ Wt) {
  __shared__ int lh[NB];
  int b = blockIdx.x;
  int tid = threadIdx.x;
  if (b < NBLK) {
    for (int i = tid; i < NB; i += 256) lh[i] = 0;
    __syncthreads();
    const int EPB = (E + NBLK - 1) / NBLK;
    int e0 = b * EPB;
    int e1 = min(e0 + EPB, E);
    for (int e = e0 + tid; e < e1; e += 256) atomicAdd(&lh[dst[e] / BN], 1);
    __syncthreads();
    for (int i = tid; i < NB; i += 256) M[i * NBLK + b] = lh[i];
  } else if (b < NBLK + GC) {
    int i = (b - NBLK) * 256 + tid;
    if (i < total4) {
      float4 v = ((const float4*)X)[i];
      ushort4 o;
      o.x = (unsigned short)bf16r(v.x);
      o.y = (unsigned short)bf16r(v.y);
      o.z = (unsigned short)bf16r(v.z);
      o.w = (unsigned short)bf16r(v.w);
      ((ushort4*)Xb)[i] = o;
    }
  } else {
    int i = (b - NBLK - GC) * 256 + tid;
    if (i < 3 * 16384) {
      int l = i >> 14;
      int r = i & 16383;
      int nn = r >> 7, kk = r & 127;
      const float* W = (l == 0) ? W0 : (l == 1) ? W1 : W2;
      Wt[i] = (unsigned short)bf16r(W[kk * 128 + nn]);
    }
  }
}

// ---------------- hierarchical scan of M (flat, bucket-major) ----------------

__global__ __launch_bounds__(256) void k_blocksum(const int* __restrict__ cnt, int* __restrict__ bsum, int n) {
  int i = blockIdx.x * 256 + threadIdx.x;
  int v = (i < n) ? cnt[i] : 0;
#pragma unroll
  for (int off = 32; off > 0; off >>= 1) v += __shfl_down(v, off);
  __shared__ int ws[4];
  if ((threadIdx.x & 63) == 0) ws[threadIdx.x >> 6] = v;
  __syncthreads();
  if (threadIdx.x == 0) bsum[blockIdx.x] = ws[0] + ws[1] + ws[2] + ws[3];
}

__global__ __launch_bounds__(512) void k_scanb2(const int* __restrict__ bsum, int* __restrict__ boff, int nb) {
  __shared__ int s[512];
  int t = threadIdx.x;
  int v = (t < nb) ? bsum[t] : 0;
  s[t] = v;
  __syncthreads();
#pragma unroll
  for (int off = 1; off < 512; off <<= 1) {
    int u = (t >= off) ? s[t - off] : 0;
    __syncthreads();
    s[t] += u;
    __syncthreads();
  }
  if (t < nb) boff[t] = s[t] - v;  // exclusive
}

__global__ __launch_bounds__(256) void k_scanm(int* __restrict__ M, const int* __restrict__ boff,
                                               int* __restrict__ bbase, int flatN, int Etot) {
  __shared__ int s[256];
  int t = threadIdx.x;
  int i = blockIdx.x * 256 + t;
  int v = (i < flatN) ? M[i] : 0;
  s[t] = v;
  __syncthreads();
#pragma unroll
  for (int off = 1; off < 256; off <<= 1) {
    int u = (t >= off) ? s[t - off] : 0;
    __syncthreads();
    s[t] += u;
    __syncthreads();
  }
  int ex = s[t] - v + boff[blockIdx.x];
  if (i < flatN) {
    M[i] = ex;
    if ((i & (NBLK - 1)) == 0) bbase[i / NBLK] = ex;
  }
  if (i == 0) bbase[NB] = Etot;
}

// ---------------- pass B + layer-0 GEMM ----------------

__global__ __launch_bounds__(256) void k_pre2(const unsigned short* __restrict__ Zb,
                                              const unsigned short* __restrict__ Wt,
                                              unsigned short* __restrict__ H, int n, int GG,
                                              const int* __restrict__ src, const int* __restrict__ dst,
                                              const float* __restrict__ ew, const int* __restrict__ M,
                                              uint2* __restrict__ part, int E) {
  __shared__ int lcur[NB];
  int b = blockIdx.x;
  if (b < GG) {
    int lane = threadIdx.x & 63;
    int wid  = threadIdx.x >> 6;
    int row0 = b * 16;
    int r  = lane & 15;
    int kg = lane >> 4;
    int c0 = wid * 32;
    const size_t abase  = (size_t)(row0 + r) * 128 + kg * 8;
    const size_t b0base = (size_t)(c0 + r) * 128 + kg * 8;
    const size_t b1base = (size_t)(c0 + 16 + r) * 128 + kg * 8;
    f32x4 acc0 = {0.f, 0.f, 0.f, 0.f};
    f32x4 acc1 = {0.f, 0.f, 0.f, 0.f};
#pragma unroll
    for (int k0 = 0; k0 < 128; k0 += 32) {
      bf16x8 a  = *(const bf16x8*)&Zb[abase + k0];
      bf16x8 b0 = *(const bf16x8*)&Wt[b0base + k0];
      bf16x8 b1 = *(const bf16x8*)&Wt[b1base + k0];
      acc0 = __builtin_amdgcn_mfma_f32_16x16x32_bf16(a, b0, acc0, 0, 0, 0);
      acc1 = __builtin_amdgcn_mfma_f32_16x16x32_bf16(a, b1, acc1, 0, 0, 0);
    }
    int orow = row0 + kg * 4;
#pragma unroll
    for (int j = 0; j < 4; ++j) {
      H[(size_t)(orow + j) * 128 + c0 + r]      = (unsigned short)bf16r(acc0[j]);
      H[(size_t)(orow + j) * 128 + c0 + 16 + r] = (unsigned short)bf16r(acc1[j]);
    }
  } else {
    int blk = b - GG;
    int tid = threadIdx.x;
    for (int i = tid; i < NB; i += 256) lcur[i] = M[i * NBLK + blk];
    __syncthreads();
    const int EPB = (E + NBLK - 1) / NBLK;
    int e0 = blk * EPB;
    int e1 = min(e0 + EPB, E);
    for (int e = e0 + tid; e < e1; e += 256) {
      int d = dst[e];
      int bkt = d / BN;
      int dlow = d - bkt * BN;
      int p = atomicAdd(&lcur[bkt], 1);
      uint2 rec;
      rec.x = (unsigned)src[e] | ((unsigned)dlow << 24);
      rec.y = __float_as_uint(ew[e]);
      part[p] = rec;
    }
  }
}

// ---------------- pass C1: per-bucket degree -> dis ----------------

__global__ __launch_bounds__(256) void k_deg(const uint2* __restrict__ part, const int* __restrict__ bbase,
                                             float* __restrict__ dis, int n) {
  __shared__ float ldeg[BN];
  int b = blockIdx.x;
  int tid = threadIdx.x;
  int base = bbase[b];
  int cnt = bbase[b + 1] - base;
  for (int i = tid; i < BN; i += 256) ldeg[i] = 0.f;
  __syncthreads();
  for (int i = tid; i < cnt; i += 256) {
    uint2 r = part[base + i];
    atomicAdd(&ldeg[r.x >> 24], __uint_as_float(r.y));
  }
  __syncthreads();
  for (int t = tid; t < BN; t += 256) dis[b * BN + t] = rsqrtf(1.0f + ldeg[t]);
}

// ---------------- pass C2: per-bucket counting sort -> csr {src24, w=dis[src]*ew} ----------------

__global__ __launch_bounds__(256) void k_bsort(const uint2* __restrict__ part, const int* __restrict__ bbase,
                                               const float* __restrict__ dis, uint2* __restrict__ csr,
                                               int* __restrict__ rowptr, int n, int E) {
  __shared__ uint2 stage[CAP];
  __shared__ int lh[BN];
  __shared__ int s[256];
  int b = blockIdx.x;
  int tid = threadIdx.x;
  int base = bbase[b];
  int cnt = bbase[b + 1] - base;
  for (int i = tid; i < BN; i += 256) lh[i] = 0;
  __syncthreads();
  for (int i = tid; i < cnt; i += 256) {
    uint2 r = part[base + i];
    if (i < CAP) stage[i] = r;
    atomicAdd(&lh[r.x >> 24], 1);
  }
  __syncthreads();
  int v = (tid < BN) ? lh[tid] : 0;
  s[tid] = v;
  __syncthreads();
#pragma unroll
  for (int off = 1; off < 256; off <<= 1) {
    int u = (tid >= off) ? s[tid - off] : 0;
    __syncthreads();
    s[tid] += u;
    __syncthreads();
  }
  int ex = s[tid] - v;  // exclusive node offset within bucket
  if (tid < BN) {
    lh[tid] = ex;  // becomes running cursor
    rowptr[b * BN + tid] = base + ex;
  }
  if (b == 0 && tid == 0) rowptr[n] = E;
  __syncthreads();
  for (int i = tid; i < cnt; i += 256) {
    uint2 r = (i < CAP) ? stage[i] : part[base + i];
    int dlow = r.x >> 24;
    unsigned srcv = r.x & 0x00FFFFFFu;
    float w = __uint_as_float(r.y) * dis[srcv];
    int p = atomicAdd(&lh[dlow], 1);
    uint2 o;
    o.x = srcv;
    o.y = __float_as_uint(w);
    csr[base + p] = o;
  }
}

// ---------------- per-layer: GEMM via MFMA bf16 (layers 1,2) ----------------

__global__ __launch_bounds__(256) void k_gemm(const unsigned short* __restrict__ Zb,
                                              const unsigned short* __restrict__ Wt,
                                              unsigned short* __restrict__ H, int n) {
  int lane = threadIdx.x & 63;
  int wid  = threadIdx.x >> 6;
  int row0 = blockIdx.x * 16;
  int r  = lane & 15;
  int kg = lane >> 4;
  int c0 = wid * 32;
  const size_t abase  = (size_t)(row0 + r) * 128 + kg * 8;
  const size_t b0base = (size_t)(c0 + r) * 128 + kg * 8;
  const size_t b1base = (size_t)(c0 + 16 + r) * 128 + kg * 8;
  f32x4 acc0 = {0.f, 0.f, 0.f, 0.f};
  f32x4 acc1 = {0.f, 0.f, 0.f, 0.f};
#pragma unroll
  for (int k0 = 0; k0 < 128; k0 += 32) {
    bf16x8 a  = *(const bf16x8*)&Zb[abase + k0];
    bf16x8 b0 = *(const bf16x8*)&Wt[b0base + k0];
    bf16x8 b1 = *(const bf16x8*)&Wt[b1base + k0];
    acc0 = __builtin_amdgcn_mfma_f32_16x16x32_bf16(a, b0, acc0, 0, 0, 0);
    acc1 = __builtin_amdgcn_mfma_f32_16x16x32_bf16(a, b1, acc1, 0, 0, 0);
  }
  int orow = row0 + kg * 4;
#pragma unroll
  for (int j = 0; j < 4; ++j) {
    H[(size_t)(orow + j) * 128 + c0 + r]      = (unsigned short)bf16r(acc0[j]);
    H[(size_t)(orow + j) * 128 + c0 + 16 + r] = (unsigned short)bf16r(acc1[j]);
  }
}

// ---------------- per-layer: tiled aggregation + bias + relu ----------------
// 2D grid: blockIdx.x = node group (4 waves), blockIdx.y = feature tile t.
// One wave per (node, tile). Lane group g in [0,4) handles edge e+g; its 16
// lanes gather the edge's 64B slice line (tile t of src row) -> one cache
// line per edge-gather; tile working set 3.2MB = L2-resident per XCD.
// Cross-group reduce via shfl_xor(16,32). w = dis[src]*ew pre-folded in csr.

__global__ __launch_bounds__(256) void k_agg(const unsigned* __restrict__ Hb, const int* __restrict__ rowptr,
                                             const f2v* __restrict__ csr, const float* __restrict__ dis,
                                             const float* __restrict__ bias, unsigned* __restrict__ outb,
                                             float* __restrict__ outf, int n) {
  int node = __builtin_amdgcn_readfirstlane(blockIdx.x * 4 + (threadIdx.x >> 6));
  if (node >= n) return;
  int lane = threadIdx.x & 63;
  int g = lane >> 4;                               // edge group 0..3
  int col = (blockIdx.y << 4) + (lane & 15);       // dword col in [0,64)
  float ax0 = 0.f, ay0 = 0.f, ax1 = 0.f, ay1 = 0.f;
  int e = rowptr[node];
  const int end = rowptr[node + 1];
  const int last = end - 1;
  for (; e < end; e += 8) {
    int e0 = e + g, e1 = e + 4 + g;
    f2v r0 = __builtin_nontemporal_load(&csr[min(e0, last)]);
    f2v r1 = __builtin_nontemporal_load(&csr[min(e1, last)]);
    int s0 = __float_as_int(r0.x);
    int s1 = __float_as_int(r1.x);
    float w0 = (e0 < end) ? r0.y : 0.f;
    float w1 = (e1 < end) ? r1.y : 0.f;
    unsigned g0 = Hb[(size_t)s0 * 64 + col];
    unsigned g1 = Hb[(size_t)s1 * 64 + col];
    ax0 = fmaf(__uint_as_float(g0 << 16), w0, ax0); ay0 = fmaf(__uint_as_float(g0 & 0xffff0000u), w0, ay0);
    ax1 = fmaf(__uint_as_float(g1 << 16), w1, ax1); ay1 = fmaf(__uint_as_float(g1 & 0xffff0000u), w1, ay1);
  }
  float ax = ax0 + ax1, ay = ay0 + ay1;
  ax += __shfl_xor(ax, 16); ay += __shfl_xor(ay, 16);
  ax += __shfl_xor(ax, 32); ay += __shfl_xor(ay, 32);
  float dn = dis[node];
  float sn = dn * dn;
  unsigned hv = Hb[(size_t)node * 64 + col];
  float hvx = __uint_as_float(hv << 16);
  float hvy = __uint_as_float(hv & 0xffff0000u);
  float2 bv = ((const float2*)bias)[col];
  float ox = fmaxf(fmaf(dn, ax, fmaf(sn, hvx, bv.x)), 0.f);
  float oy = fmaxf(fmaf(dn, ay, fmaf(sn, hvy, bv.y)), 0.f);
  if (lane < 16) {
    if (outb) {
      outb[(size_t)node * 64 + col] = bf16r(ox) | (bf16r(oy) << 16);
    } else {
      f2v o; o.x = ox; o.y = oy;
      __builtin_nontemporal_store(o, (f2v*)outf + (size_t)node * 64 + col);
    }
  }
}

// ---------------- host ----------------

extern "C" void kernel_launch(void* const* d_in, const int* in_sizes, int n_in,
                              void* d_out, int out_size, void* d_ws, size_t ws_size,
                              hipStream_t stream) {
  const float* x  = (const float*)d_in[0];
  const int*   ei = (const int*)d_in[1];   // int32: [2, E] row-major
  const float* ew = (const float*)d_in[2];
  const float* W0 = (const float*)d_in[3];
  const float* W1 = (const float*)d_in[5];
  const float* W2 = (const float*)d_in[7];
  const float* bl[3] = {(const float*)d_in[4], (const float*)d_in[6], (const float*)d_in[8]};

  const int n = in_sizes[0] / D;   // 50000 == NB*BN
  const int E = in_sizes[1] / 2;
  const int* src = ei;
  const int* dst = ei + E;

  char* p = (char*)d_ws;
  unsigned short* Zb     = (unsigned short*)p; p += (size_t)n * D * 2;  // xb for layer 0
  unsigned short* H      = (unsigned short*)p; p += (size_t)n * D * 2;
  float*          dis    = (float*)p;          p += (size_t)n * 4;
  int*            rowptr = (int*)p;            p += (size_t)(n + 1) * 4;
  int*            M      = (int*)p;            p += (size_t)NB * NBLK * 4;
  int*            bbase  = (int*)p;            p += (size_t)(NB + 1) * 4;
  int*            bsum2  = (int*)p;            p += 512 * 4;
  int*            boff2  = (int*)p;            p += 512 * 4;
  uint2*          part   = (uint2*)p;          p += (size_t)E * 8;
  uint2*          csr    = (uint2*)p;          p += (size_t)E * 8;
  unsigned short* Wt     = (unsigned short*)p; p += 3 * 16384 * 2;
  (void)ws_size; (void)n_in;

  const int total4 = n * D / 4;            // 1.6M
  const int GC = (total4 + 255) / 256;     // 6250
  const int GW = (3 * 16384 + 255) / 256;  // 192
  const int GG = n / 16;                   // 3125 (n % 16 == 0)
  const int flatN = NB * NBLK;             // 128000
  const int GS = flatN / 256;              // 500

  k_pre1<<<NBLK + GC + GW, 256, 0, stream>>>(dst, M, E, x, Zb, total4, GC, W0, W1, W2, Wt);
  k_blocksum<<<GS, 256, 0, stream>>>(M, bsum2, flatN);
  k_scanb2<<<1, 512, 0, stream>>>(bsum2, boff2, GS);
  k_scanm<<<GS, 256, 0, stream>>>(M, boff2, bbase, flatN, E);
  k_pre2<<<GG + NBLK, 256, 0, stream>>>(Zb, Wt, H, n, GG, src, dst, ew, M, part, E);
  k_deg<<<NB, 256, 0, stream>>>(part, bbase, dis, n);
  k_bsort<<<NB, 256, 0, stream>>>(part, bbase, dis, csr, rowptr, n, E);

  float* outp = (float*)d_out;
  dim3 agrid((n + 3) / 4, NT);
  // layer 0 aggregation (gemm0 already done inside k_pre2)
  k_agg<<<agrid, 256, 0, stream>>>((const unsigned*)H, rowptr, (const f2v*)csr, dis, bl[0], (unsigned*)Zb, outp, n);
  for (int l = 1; l < 3; ++l) {
    k_gemm<<<GG, 256, 0, stream>>>(Zb, Wt + l * 16384, H, n);
    unsigned* ob = (l == 2) ? nullptr : (unsigned*)Zb;
    k_agg<<<agrid, 256, 0, stream>>>((const unsigned*)H, rowptr, (const f2v*)csr, dis, bl[l], ob, outp, n);
  }
}

// Round 17
// 235.706 us; speedup vs baseline: 1.7100x; 1.7100x over previous
//
#include <hip/hip_runtime.h>

#define D 128
#define NB 250    // node buckets
#define BN 200    // nodes per bucket (NB*BN == n == 50000)
#define NBLK 512  // histogram/partition blocks (power of 2)
#define CAP 7168  // LDS-staged edges per bucket; global-read fallback past this

typedef float f2v __attribute__((ext_vector_type(2)));
typedef short bf16x8 __attribute__((ext_vector_type(8)));
typedef float f32x4 __attribute__((ext_vector_type(4)));

// bf16 round-to-nearest-even
__device__ __forceinline__ unsigned bf16r(float f) {
  unsigned u = __float_as_uint(f);
  return (u + 0x7fffu + ((u >> 16) & 1u)) >> 16;
}

// ---------------- pass A + converts ----------------

__global__ __launch_bounds__(256) void k_pre1(const int* __restrict__ dst, int* __restrict__ M, int E,
                                              const float* __restrict__ X, unsigned short* __restrict__ Xb,
                                              int total4, int GC,
                                              const float* __restrict__ W0, const float* __restrict__ W1,
                                              const float* __restrict__ W2, unsigned short* __restrict__ Wt) {
  __shared__ int lh[NB];
  int b = blockIdx.x;
  int tid = threadIdx.x;
  if (b < NBLK) {
    for (int i = tid; i < NB; i += 256) lh[i] = 0;
    __syncthreads();
    const int EPB = (E + NBLK - 1) / NBLK;
    int e0 = b * EPB;
    int e1 = min(e0 + EPB, E);
    for (int e = e0 + tid; e < e1; e += 256) atomicAdd(&lh[dst[e] / BN], 1);
    __syncthreads();
    for (int i = tid; i < NB; i += 256) M[i * NBLK + b] = lh[i];
  } else if (b < NBLK + GC) {
    int i = (b - NBLK) * 256 + tid;
    if (i < total4) {
      float4 v = ((const float4*)X)[i];
      ushort4 o;
      o.x = (unsigned short)bf16r(v.x);
      o.y = (unsigned short)bf16r(v.y);
      o.z = (unsigned short)bf16r(v.z);
      o.w = (unsigned short)bf16r(v.w);
      ((ushort4*)Xb)[i] = o;
    }
  } else {
    int i = (b - NBLK - GC) * 256 + tid;
    if (i < 3 * 16384) {
      int l = i >> 14;
      int r = i & 16383;
      int nn = r >> 7, kk = r & 127;
      const float* W = (l == 0) ? W0 : (l == 1) ? W1 : W2;
      Wt[i] = (unsigned short)bf16r(W[kk * 128 + nn]);
    }
  }
}

// ---------------- hierarchical scan of M (flat, bucket-major) ----------------

__global__ __launch_bounds__(256) void k_blocksum(const int* __restrict__ cnt, int* __restrict__ bsum, int n) {
  int i = blockIdx.x * 256 + threadIdx.x;
  int v = (i < n) ? cnt[i] : 0;
#pragma unroll
  for (int off = 32; off > 0; off >>= 1) v += __shfl_down(v, off);
  __shared__ int ws[4];
  if ((threadIdx.x & 63) == 0) ws[threadIdx.x >> 6] = v;
  __syncthreads();
  if (threadIdx.x == 0) bsum[blockIdx.x] = ws[0] + ws[1] + ws[2] + ws[3];
}

__global__ __launch_bounds__(512) void k_scanb2(const int* __restrict__ bsum, int* __restrict__ boff, int nb) {
  __shared__ int s[512];
  int t = threadIdx.x;
  int v = (t < nb) ? bsum[t] : 0;
  s[t] = v;
  __syncthreads();
#pragma unroll
  for (int off = 1; off < 512; off <<= 1) {
    int u = (t >= off) ? s[t - off] : 0;
    __syncthreads();
    s[t] += u;
    __syncthreads();
  }
  if (t < nb) boff[t] = s[t] - v;  // exclusive
}

__global__ __launch_bounds__(256) void k_scanm(int* __restrict__ M, const int* __restrict__ boff,
                                               int* __restrict__ bbase, int flatN, int Etot) {
  __shared__ int s[256];
  int t = threadIdx.x;
  int i = blockIdx.x * 256 + t;
  int v = (i < flatN) ? M[i] : 0;
  s[t] = v;
  __syncthreads();
#pragma unroll
  for (int off = 1; off < 256; off <<= 1) {
    int u = (t >= off) ? s[t - off] : 0;
    __syncthreads();
    s[t] += u;
    __syncthreads();
  }
  int ex = s[t] - v + boff[blockIdx.x];
  if (i < flatN) {
    M[i] = ex;
    if ((i & (NBLK - 1)) == 0) bbase[i / NBLK] = ex;
  }
  if (i == 0) bbase[NB] = Etot;
}

// ---------------- pass B + layer-0 GEMM ----------------

__global__ __launch_bounds__(256) void k_pre2(const unsigned short* __restrict__ Zb,
                                              const unsigned short* __restrict__ Wt,
                                              unsigned short* __restrict__ H, int n, int GG,
                                              const int* __restrict__ src, const int* __restrict__ dst,
                                              const float* __restrict__ ew, const int* __restrict__ M,
                                              uint2* __restrict__ part, int E) {
  __shared__ int lcur[NB];
  int b = blockIdx.x;
  if (b < GG) {
    int lane = threadIdx.x & 63;
    int wid  = threadIdx.x >> 6;
    int row0 = b * 16;
    int r  = lane & 15;
    int kg = lane >> 4;
    int c0 = wid * 32;
    const size_t abase  = (size_t)(row0 + r) * 128 + kg * 8;
    const size_t b0base = (size_t)(c0 + r) * 128 + kg * 8;
    const size_t b1base = (size_t)(c0 + 16 + r) * 128 + kg * 8;
    f32x4 acc0 = {0.f, 0.f, 0.f, 0.f};
    f32x4 acc1 = {0.f, 0.f, 0.f, 0.f};
#pragma unroll
    for (int k0 = 0; k0 < 128; k0 += 32) {
      bf16x8 a  = *(const bf16x8*)&Zb[abase + k0];
      bf16x8 b0 = *(const bf16x8*)&Wt[b0base + k0];
      bf16x8 b1 = *(const bf16x8*)&Wt[b1base + k0];
      acc0 = __builtin_amdgcn_mfma_f32_16x16x32_bf16(a, b0, acc0, 0, 0, 0);
      acc1 = __builtin_amdgcn_mfma_f32_16x16x32_bf16(a, b1, acc1, 0, 0, 0);
    }
    int orow = row0 + kg * 4;
#pragma unroll
    for (int j = 0; j < 4; ++j) {
      H[(size_t)(orow + j) * 128 + c0 + r]      = (unsigned short)bf16r(acc0[j]);
      H[(size_t)(orow + j) * 128 + c0 + 16 + r] = (unsigned short)bf16r(acc1[j]);
    }
  } else {
    int blk = b - GG;
    int tid = threadIdx.x;
    for (int i = tid; i < NB; i += 256) lcur[i] = M[i * NBLK + blk];
    __syncthreads();
    const int EPB = (E + NBLK - 1) / NBLK;
    int e0 = blk * EPB;
    int e1 = min(e0 + EPB, E);
    for (int e = e0 + tid; e < e1; e += 256) {
      int d = dst[e];
      int bkt = d / BN;
      int dlow = d - bkt * BN;
      int p = atomicAdd(&lcur[bkt], 1);
      uint2 rec;
      rec.x = (unsigned)src[e] | ((unsigned)dlow << 24);
      rec.y = __float_as_uint(ew[e]);
      part[p] = rec;
    }
  }
}

// ---------------- pass C1: per-bucket degree -> dis ----------------

__global__ __launch_bounds__(256) void k_deg(const uint2* __restrict__ part, const int* __restrict__ bbase,
                                             float* __restrict__ dis, int n) {
  __shared__ float ldeg[BN];
  int b = blockIdx.x;
  int tid = threadIdx.x;
  int base = bbase[b];
  int cnt = bbase[b + 1] - base;
  for (int i = tid; i < BN; i += 256) ldeg[i] = 0.f;
  __syncthreads();
  for (int i = tid; i < cnt; i += 256) {
    uint2 r = part[base + i];
    atomicAdd(&ldeg[r.x >> 24], __uint_as_float(r.y));
  }
  __syncthreads();
  for (int t = tid; t < BN; t += 256) dis[b * BN + t] = rsqrtf(1.0f + ldeg[t]);
}

// ---------------- pass C2: per-bucket counting sort -> csr {src24, w=dis[src]*ew} ----------------

__global__ __launch_bounds__(256) void k_bsort(const uint2* __restrict__ part, const int* __restrict__ bbase,
                                               const float* __restrict__ dis, uint2* __restrict__ csr,
                                               int* __restrict__ rowptr, int n, int E) {
  __shared__ uint2 stage[CAP];
  __shared__ int lh[BN];
  __shared__ int s[256];
  int b = blockIdx.x;
  int tid = threadIdx.x;
  int base = bbase[b];
  int cnt = bbase[b + 1] - base;
  for (int i = tid; i < BN; i += 256) lh[i] = 0;
  __syncthreads();
  for (int i = tid; i < cnt; i += 256) {
    uint2 r = part[base + i];
    if (i < CAP) stage[i] = r;
    atomicAdd(&lh[r.x >> 24], 1);
  }
  __syncthreads();
  int v = (tid < BN) ? lh[tid] : 0;
  s[tid] = v;
  __syncthreads();
#pragma unroll
  for (int off = 1; off < 256; off <<= 1) {
    int u = (tid >= off) ? s[tid - off] : 0;
    __syncthreads();
    s[tid] += u;
    __syncthreads();
  }
  int ex = s[tid] - v;  // exclusive node offset within bucket
  if (tid < BN) {
    lh[tid] = ex;  // becomes running cursor
    rowptr[b * BN + tid] = base + ex;
  }
  if (b == 0 && tid == 0) rowptr[n] = E;
  __syncthreads();
  for (int i = tid; i < cnt; i += 256) {
    uint2 r = (i < CAP) ? stage[i] : part[base + i];
    int dlow = r.x >> 24;
    unsigned srcv = r.x & 0x00FFFFFFu;
    float w = __uint_as_float(r.y) * dis[srcv];
    int p = atomicAdd(&lh[dlow], 1);
    uint2 o;
    o.x = srcv;
    o.y = __float_as_uint(w);
    csr[base + p] = o;
  }
}

// ---------------- per-layer: GEMM via MFMA bf16 (layers 1,2) ----------------

__global__ __launch_bounds__(256) void k_gemm(const unsigned short* __restrict__ Zb,
                                              const unsigned short* __restrict__ Wt,
                                              unsigned short* __restrict__ H, int n) {
  int lane = threadIdx.x & 63;
  int wid  = threadIdx.x >> 6;
  int row0 = blockIdx.x * 16;
  int r  = lane & 15;
  int kg = lane >> 4;
  int c0 = wid * 32;
  const size_t abase  = (size_t)(row0 + r) * 128 + kg * 8;
  const size_t b0base = (size_t)(c0 + r) * 128 + kg * 8;
  const size_t b1base = (size_t)(c0 + 16 + r) * 128 + kg * 8;
  f32x4 acc0 = {0.f, 0.f, 0.f, 0.f};
  f32x4 acc1 = {0.f, 0.f, 0.f, 0.f};
#pragma unroll
  for (int k0 = 0; k0 < 128; k0 += 32) {
    bf16x8 a  = *(const bf16x8*)&Zb[abase + k0];
    bf16x8 b0 = *(const bf16x8*)&Wt[b0base + k0];
    bf16x8 b1 = *(const bf16x8*)&Wt[b1base + k0];
    acc0 = __builtin_amdgcn_mfma_f32_16x16x32_bf16(a, b0, acc0, 0, 0, 0);
    acc1 = __builtin_amdgcn_mfma_f32_16x16x32_bf16(a, b1, acc1, 0, 0, 0);
  }
  int orow = row0 + kg * 4;
#pragma unroll
  for (int j = 0; j < 4; ++j) {
    H[(size_t)(orow + j) * 128 + c0 + r]      = (unsigned short)bf16r(acc0[j]);
    H[(size_t)(orow + j) * 128 + c0 + 16 + r] = (unsigned short)bf16r(acc1[j]);
  }
}

// ---------------- per-layer: aggregation + bias + relu ----------------
// One wave per node; lane reads uint2 (4 bf16 feats), 32 lanes cover the
// 256B row -> 2 edges per gather instruction (half-waves g=0/1). 16-edge
// unroll = 8 gathers = 64 lines in flight/wave. w pre-folded. Tail is a
// clamped 2-edge loop (handles any remainder — R16 dropped deg%4==3 edges).

__global__ __launch_bounds__(256) void k_agg(const uint2* __restrict__ Hb2, const int* __restrict__ rowptr,
                                             const f2v* __restrict__ csr, const float* __restrict__ dis,
                                             const float* __restrict__ bias, uint2* __restrict__ outb,
                                             float* __restrict__ outf, int n) {
  int node = __builtin_amdgcn_readfirstlane(blockIdx.x * 4 + (threadIdx.x >> 6));
  if (node >= n) return;
  int lane = threadIdx.x & 63;
  int g  = lane >> 5;    // edge parity (half-wave)
  int l2 = lane & 31;    // uint2 col within row
  float a0 = 0.f, a1 = 0.f, a2 = 0.f, a3 = 0.f;
  float b0 = 0.f, b1 = 0.f, b2 = 0.f, b3 = 0.f;
  int e = rowptr[node];
  const int end = rowptr[node + 1];
  const int last = end - 1;
  for (; e + 16 <= end; e += 16) {
    f2v r0 = __builtin_nontemporal_load(&csr[e + g]);
    f2v r1 = __builtin_nontemporal_load(&csr[e + 2 + g]);
    f2v r2 = __builtin_nontemporal_load(&csr[e + 4 + g]);
    f2v r3 = __builtin_nontemporal_load(&csr[e + 6 + g]);
    f2v r4 = __builtin_nontemporal_load(&csr[e + 8 + g]);
    f2v r5 = __builtin_nontemporal_load(&csr[e + 10 + g]);
    f2v r6 = __builtin_nontemporal_load(&csr[e + 12 + g]);
    f2v r7 = __builtin_nontemporal_load(&csr[e + 14 + g]);
    uint2 g0 = Hb2[(size_t)__float_as_int(r0.x) * 32 + l2];
    uint2 g1 = Hb2[(size_t)__float_as_int(r1.x) * 32 + l2];
    uint2 g2 = Hb2[(size_t)__float_as_int(r2.x) * 32 + l2];
    uint2 g3 = Hb2[(size_t)__float_as_int(r3.x) * 32 + l2];
    uint2 g4 = Hb2[(size_t)__float_as_int(r4.x) * 32 + l2];
    uint2 g5 = Hb2[(size_t)__float_as_int(r5.x) * 32 + l2];
    uint2 g6 = Hb2[(size_t)__float_as_int(r6.x) * 32 + l2];
    uint2 g7 = Hb2[(size_t)__float_as_int(r7.x) * 32 + l2];
    a0 = fmaf(__uint_as_float(g0.x << 16), r0.y, a0); a1 = fmaf(__uint_as_float(g0.x & 0xffff0000u), r0.y, a1);
    a2 = fmaf(__uint_as_float(g0.y << 16), r0.y, a2); a3 = fmaf(__uint_as_float(g0.y & 0xffff0000u), r0.y, a3);
    b0 = fmaf(__uint_as_float(g1.x << 16), r1.y, b0); b1 = fmaf(__uint_as_float(g1.x & 0xffff0000u), r1.y, b1);
    b2 = fmaf(__uint_as_float(g1.y << 16), r1.y, b2); b3 = fmaf(__uint_as_float(g1.y & 0xffff0000u), r1.y, b3);
    a0 = fmaf(__uint_as_float(g2.x << 16), r2.y, a0); a1 = fmaf(__uint_as_float(g2.x & 0xffff0000u), r2.y, a1);
    a2 = fmaf(__uint_as_float(g2.y << 16), r2.y, a2); a3 = fmaf(__uint_as_float(g2.y & 0xffff0000u), r2.y, a3);
    b0 = fmaf(__uint_as_float(g3.x << 16), r3.y, b0); b1 = fmaf(__uint_as_float(g3.x & 0xffff0000u), r3.y, b1);
    b2 = fmaf(__uint_as_float(g3.y << 16), r3.y, b2); b3 = fmaf(__uint_as_float(g3.y & 0xffff0000u), r3.y, b3);
    a0 = fmaf(__uint_as_float(g4.x << 16), r4.y, a0); a1 = fmaf(__uint_as_float(g4.x & 0xffff0000u), r4.y, a1);
    a2 = fmaf(__uint_as_float(g4.y << 16), r4.y, a2); a3 = fmaf(__uint_as_float(g4.y & 0xffff0000u), r4.y, a3);
    b0 = fmaf(__uint_as_float(g5.x << 16), r5.y, b0); b1 = fmaf(__uint_as_float(g5.x & 0xffff0000u), r5.y, b1);
    b2 = fmaf(__uint_as_float(g5.y << 16), r5.y, b2); b3 = fmaf(__uint_as_float(g5.y & 0xffff0000u), r5.y, b3);
    a0 = fmaf(__uint_as_float(g6.x << 16), r6.y, a0); a1 = fmaf(__uint_as_float(g6.x & 0xffff0000u), r6.y, a1);
    a2 = fmaf(__uint_as_float(g6.y << 16), r6.y, a2); a3 = fmaf(__uint_as_float(g6.y & 0xffff0000u), r6.y, a3);
    b0 = fmaf(__uint_as_float(g7.x << 16), r7.y, b0); b1 = fmaf(__uint_as_float(g7.x & 0xffff0000u), r7.y, b1);
    b2 = fmaf(__uint_as_float(g7.y << 16), r7.y, b2); b3 = fmaf(__uint_as_float(g7.y & 0xffff0000u), r7.y, b3);
  }
  for (; e + 4 <= end; e += 4) {
    f2v r0 = __builtin_nontemporal_load(&csr[e + g]);
    f2v r1 = __builtin_nontemporal_load(&csr[e + 2 + g]);
    uint2 g0 = Hb2[(size_t)__float_as_int(r0.x) * 32 + l2];
    uint2 g1 = Hb2[(size_t)__float_as_int(r1.x) * 32 + l2];
    a0 = fmaf(__uint_as_float(g0.x << 16), r0.y, a0); a1 = fmaf(__uint_as_float(g0.x & 0xffff0000u), r0.y, a1);
    a2 = fmaf(__uint_as_float(g0.y << 16), r0.y, a2); a3 = fmaf(__uint_as_float(g0.y & 0xffff0000u), r0.y, a3);
    b0 = fmaf(__uint_as_float(g1.x << 16), r1.y, b0); b1 = fmaf(__uint_as_float(g1.x & 0xffff0000u), r1.y, b1);
    b2 = fmaf(__uint_as_float(g1.y << 16), r1.y, b2); b3 = fmaf(__uint_as_float(g1.y & 0xffff0000u), r1.y, b3);
  }
  for (; e < end; e += 2) {   // clamped 2-edge tail: handles remainder 1..3
    int ei = e + g;
    f2v r0 = __builtin_nontemporal_load(&csr[min(ei, last)]);
    float w0 = (ei < end) ? r0.y : 0.f;
    uint2 g0 = Hb2[(size_t)__float_as_int(r0.x) * 32 + l2];
    a0 = fmaf(__uint_as_float(g0.x << 16), w0, a0); a1 = fmaf(__uint_as_float(g0.x & 0xffff0000u), w0, a1);
    a2 = fmaf(__uint_as_float(g0.y << 16), w0, a2); a3 = fmaf(__uint_as_float(g0.y & 0xffff0000u), w0, a3);
  }
  float s0 = a0 + b0, s1 = a1 + b1, s2 = a2 + b2, s3 = a3 + b3;
  s0 += __shfl_xor(s0, 32);
  s1 += __shfl_xor(s1, 32);
  s2 += __shfl_xor(s2, 32);
  s3 += __shfl_xor(s3, 32);
  float dn = dis[node];
  float sn = dn * dn;
  uint2 hv = Hb2[(size_t)node * 32 + l2];
  float h0 = __uint_as_float(hv.x << 16), h1 = __uint_as_float(hv.x & 0xffff0000u);
  float h2 = __uint_as_float(hv.y << 16), h3 = __uint_as_float(hv.y & 0xffff0000u);
  float4 bv = ((const float4*)bias)[l2];
  float o0 = fmaxf(fmaf(dn, s0, fmaf(sn, h0, bv.x)), 0.f);
  float o1 = fmaxf(fmaf(dn, s1, fmaf(sn, h1, bv.y)), 0.f);
  float o2 = fmaxf(fmaf(dn, s2, fmaf(sn, h2, bv.z)), 0.f);
  float o3 = fmaxf(fmaf(dn, s3, fmaf(sn, h3, bv.w)), 0.f);
  if (lane < 32) {
    if (outb) {
      uint2 ov;
      ov.x = bf16r(o0) | (bf16r(o1) << 16);
      ov.y = bf16r(o2) | (bf16r(o3) << 16);
      outb[(size_t)node * 32 + l2] = ov;
    } else {
      f32x4 o = {o0, o1, o2, o3};
      __builtin_nontemporal_store(o, (f32x4*)outf + (size_t)node * 32 + l2);
    }
  }
}

// ---------------- host ----------------

extern "C" void kernel_launch(void* const* d_in, const int* in_sizes, int n_in,
                              void* d_out, int out_size, void* d_ws, size_t ws_size,
                              hipStream_t stream) {
  const float* x  = (const float*)d_in[0];
  const int*   ei = (const int*)d_in[1];   // int32: [2, E] row-major
  const float* ew = (const float*)d_in[2];
  const float* W0 = (const float*)d_in[3];
  const float* W1 = (const float*)d_in[5];
  const float* W2 = (const float*)d_in[7];
  const float* bl[3] = {(const float*)d_in[4], (const float*)d_in[6], (const float*)d_in[8]};

  const int n = in_sizes[0] / D;   // 50000 == NB*BN
  const int E = in_sizes[1] / 2;
  const int* src = ei;
  const int* dst = ei + E;

  char* p = (char*)d_ws;
  unsigned short* Zb     = (unsigned short*)p; p += (size_t)n * D * 2;  // xb for layer 0
  unsigned short* H      = (unsigned short*)p; p += (size_t)n * D * 2;
  float*          dis    = (float*)p;          p += (size_t)n * 4;
  int*            rowptr = (int*)p;            p += (size_t)(n + 1) * 4;
  int*            M      = (int*)p;            p += (size_t)NB * NBLK * 4;
  int*            bbase  = (int*)p;            p += (size_t)(NB + 1) * 4;
  int*            bsum2  = (int*)p;            p += 512 * 4;
  int*            boff2  = (int*)p;            p += 512 * 4;
  uint2*          part   = (uint2*)p;          p += (size_t)E * 8;
  uint2*          csr    = (uint2*)p;          p += (size_t)E * 8;
  unsigned short* Wt     = (unsigned short*)p; p += 3 * 16384 * 2;
  (void)ws_size; (void)n_in;

  const int total4 = n * D / 4;            // 1.6M
  const int GC = (total4 + 255) / 256;     // 6250
  const int GW = (3 * 16384 + 255) / 256;  // 192
  const int GG = n / 16;                   // 3125 (n % 16 == 0)
  const int flatN = NB * NBLK;             // 128000
  const int GS = flatN / 256;              // 500

  k_pre1<<<NBLK + GC + GW, 256, 0, stream>>>(dst, M, E, x, Zb, total4, GC, W0, W1, W2, Wt);
  k_blocksum<<<GS, 256, 0, stream>>>(M, bsum2, flatN);
  k_scanb2<<<1, 512, 0, stream>>>(bsum2, boff2, GS);
  k_scanm<<<GS, 256, 0, stream>>>(M, boff2, bbase, flatN, E);
  k_pre2<<<GG + NBLK, 256, 0, stream>>>(Zb, Wt, H, n, GG, src, dst, ew, M, part, E);
  k_deg<<<NB, 256, 0, stream>>>(part, bbase, dis, n);
  k_bsort<<<NB, 256, 0, stream>>>(part, bbase, dis, csr, rowptr, n, E);

  float* outp = (float*)d_out;
  // layer 0 aggregation (gemm0 already done inside k_pre2)
  k_agg<<<(n + 3) / 4, 256, 0, stream>>>((const uint2*)H, rowptr, (const f2v*)csr, dis, bl[0], (uint2*)Zb, outp, n);
  for (int l = 1; l < 3; ++l) {
    k_gemm<<<GG, 256, 0, stream>>>(Zb, Wt + l * 16384, H, n);
    uint2* ob = (l == 2) ? nullptr : (uint2*)Zb;
    k_agg<<<(n + 3) / 4, 256, 0, stream>>>((const uint2*)H, rowptr, (const f2v*)csr, dis, bl[l], ob, outp, n);
  }
}

// Round 18
// 202.383 us; speedup vs baseline: 1.9916x; 1.1647x over previous
//
#include <hip/hip_runtime.h>

#define D 128
#define NB 250    // node buckets
#define BN 200    // nodes per bucket (NB*BN == n == 50000)
#define NBLK 512  // histogram/partition blocks (power of 2)
#define CAP 7168  // LDS-staged edges per bucket; global-read fallback past this

typedef float f2v __attribute__((ext_vector_type(2)));
typedef short bf16x8 __attribute__((ext_vector_type(8)));
typedef float f32x4 __attribute__((ext_vector_type(4)));

// bf16 round-to-nearest-even
__device__ __forceinline__ unsigned bf16r(float f) {
  unsigned u = __float_as_uint(f);
  return (u + 0x7fffu + ((u >> 16) & 1u)) >> 16;
}

// ---------------- pass A + converts ----------------

__global__ __launch_bounds__(256) void k_pre1(const int* __restrict__ dst, int* __restrict__ M, int E,
                                              const float* __restrict__ X, unsigned short* __restrict__ Xb,
                                              int total4, int GC,
                                              const float* __restrict__ W0, const float* __restrict__ W1,
                                              const float* __restrict__ W2, unsigned short* __restrict__ Wt) {
  __shared__ int lh[NB];
  int b = blockIdx.x;
  int tid = threadIdx.x;
  if (b < NBLK) {
    for (int i = tid; i < NB; i += 256) lh[i] = 0;
    __syncthreads();
    const int EPB = (E + NBLK - 1) / NBLK;
    int e0 = b * EPB;
    int e1 = min(e0 + EPB, E);
    for (int e = e0 + tid; e < e1; e += 256) atomicAdd(&lh[dst[e] / BN], 1);
    __syncthreads();
    for (int i = tid; i < NB; i += 256) M[i * NBLK + b] = lh[i];
  } else if (b < NBLK + GC) {
    int i = (b - NBLK) * 256 + tid;
    if (i < total4) {
      float4 v = ((const float4*)X)[i];
      ushort4 o;
      o.x = (unsigned short)bf16r(v.x);
      o.y = (unsigned short)bf16r(v.y);
      o.z = (unsigned short)bf16r(v.z);
      o.w = (unsigned short)bf16r(v.w);
      ((ushort4*)Xb)[i] = o;
    }
  } else {
    int i = (b - NBLK - GC) * 256 + tid;
    if (i < 3 * 16384) {
      int l = i >> 14;
      int r = i & 16383;
      int nn = r >> 7, kk = r & 127;
      const float* W = (l == 0) ? W0 : (l == 1) ? W1 : W2;
      Wt[i] = (unsigned short)bf16r(W[kk * 128 + nn]);
    }
  }
}

// ---------------- hierarchical scan of M (flat, bucket-major) ----------------

__global__ __launch_bounds__(256) void k_blocksum(const int* __restrict__ cnt, int* __restrict__ bsum, int n) {
  int i = blockIdx.x * 256 + threadIdx.x;
  int v = (i < n) ? cnt[i] : 0;
#pragma unroll
  for (int off = 32; off > 0; off >>= 1) v += __shfl_down(v, off);
  __shared__ int ws[4];
  if ((threadIdx.x & 63) == 0) ws[threadIdx.x >> 6] = v;
  __syncthreads();
  if (threadIdx.x == 0) bsum[blockIdx.x] = ws[0] + ws[1] + ws[2] + ws[3];
}

__global__ __launch_bounds__(512) void k_scanb2(const int* __restrict__ bsum, int* __restrict__ boff, int nb) {
  __shared__ int s[512];
  int t = threadIdx.x;
  int v = (t < nb) ? bsum[t] : 0;
  s[t] = v;
  __syncthreads();
#pragma unroll
  for (int off = 1; off < 512; off <<= 1) {
    int u = (t >= off) ? s[t - off] : 0;
    __syncthreads();
    s[t] += u;
    __syncthreads();
  }
  if (t < nb) boff[t] = s[t] - v;  // exclusive
}

__global__ __launch_bounds__(256) void k_scanm(int* __restrict__ M, const int* __restrict__ boff,
                                               int* __restrict__ bbase, int flatN, int Etot) {
  __shared__ int s[256];
  int t = threadIdx.x;
  int i = blockIdx.x * 256 + t;
  int v = (i < flatN) ? M[i] : 0;
  s[t] = v;
  __syncthreads();
#pragma unroll
  for (int off = 1; off < 256; off <<= 1) {
    int u = (t >= off) ? s[t - off] : 0;
    __syncthreads();
    s[t] += u;
    __syncthreads();
  }
  int ex = s[t] - v + boff[blockIdx.x];
  if (i < flatN) {
    M[i] = ex;
    if ((i & (NBLK - 1)) == 0) bbase[i / NBLK] = ex;
  }
  if (i == 0) bbase[NB] = Etot;
}

// ---------------- pass B + layer-0 GEMM ----------------

__global__ __launch_bounds__(256) void k_pre2(const unsigned short* __restrict__ Zb,
                                              const unsigned short* __restrict__ Wt,
                                              unsigned short* __restrict__ H, int n, int GG,
                                              const int* __restrict__ src, const int* __restrict__ dst,
                                              const float* __restrict__ ew, const int* __restrict__ M,
                                              uint2* __restrict__ part, int E) {
  __shared__ int lcur[NB];
  int b = blockIdx.x;
  if (b < GG) {
    int lane = threadIdx.x & 63;
    int wid  = threadIdx.x >> 6;
    int row0 = b * 16;
    int r  = lane & 15;
    int kg = lane >> 4;
    int c0 = wid * 32;
    const size_t abase  = (size_t)(row0 + r) * 128 + kg * 8;
    const size_t b0base = (size_t)(c0 + r) * 128 + kg * 8;
    const size_t b1base = (size_t)(c0 + 16 + r) * 128 + kg * 8;
    f32x4 acc0 = {0.f, 0.f, 0.f, 0.f};
    f32x4 acc1 = {0.f, 0.f, 0.f, 0.f};
#pragma unroll
    for (int k0 = 0; k0 < 128; k0 += 32) {
      bf16x8 a  = *(const bf16x8*)&Zb[abase + k0];
      bf16x8 b0 = *(const bf16x8*)&Wt[b0base + k0];
      bf16x8 b1 = *(const bf16x8*)&Wt[b1base + k0];
      acc0 = __builtin_amdgcn_mfma_f32_16x16x32_bf16(a, b0, acc0, 0, 0, 0);
      acc1 = __builtin_amdgcn_mfma_f32_16x16x32_bf16(a, b1, acc1, 0, 0, 0);
    }
    int orow = row0 + kg * 4;
#pragma unroll
    for (int j = 0; j < 4; ++j) {
      H[(size_t)(orow + j) * 128 + c0 + r]      = (unsigned short)bf16r(acc0[j]);
      H[(size_t)(orow + j) * 128 + c0 + 16 + r] = (unsigned short)bf16r(acc1[j]);
    }
  } else {
    int blk = b - GG;
    int tid = threadIdx.x;
    for (int i = tid; i < NB; i += 256) lcur[i] = M[i * NBLK + blk];
    __syncthreads();
    const int EPB = (E + NBLK - 1) / NBLK;
    int e0 = blk * EPB;
    int e1 = min(e0 + EPB, E);
    for (int e = e0 + tid; e < e1; e += 256) {
      int d = dst[e];
      int bkt = d / BN;
      int dlow = d - bkt * BN;
      int p = atomicAdd(&lcur[bkt], 1);
      uint2 rec;
      rec.x = (unsigned)src[e] | ((unsigned)dlow << 24);
      rec.y = __float_as_uint(ew[e]);
      part[p] = rec;
    }
  }
}

// ---------------- pass C1: per-bucket degree -> dis ----------------

__global__ __launch_bounds__(256) void k_deg(const uint2* __restrict__ part, const int* __restrict__ bbase,
                                             float* __restrict__ dis, int n) {
  __shared__ float ldeg[BN];
  int b = blockIdx.x;
  int tid = threadIdx.x;
  int base = bbase[b];
  int cnt = bbase[b + 1] - base;
  for (int i = tid; i < BN; i += 256) ldeg[i] = 0.f;
  __syncthreads();
  for (int i = tid; i < cnt; i += 256) {
    uint2 r = part[base + i];
    atomicAdd(&ldeg[r.x >> 24], __uint_as_float(r.y));
  }
  __syncthreads();
  for (int t = tid; t < BN; t += 256) dis[b * BN + t] = rsqrtf(1.0f + ldeg[t]);
}

// ---------------- pass C2: per-bucket counting sort -> csr {src, w=dis[src]*ew} ----------------

__global__ __launch_bounds__(256) void k_bsort(const uint2* __restrict__ part, const int* __restrict__ bbase,
                                               const float* __restrict__ dis, uint2* __restrict__ csr,
                                               int* __restrict__ rowptr, int n, int E) {
  __shared__ uint2 stage[CAP];
  __shared__ int lh[BN];
  __shared__ int s[256];
  int b = blockIdx.x;
  int tid = threadIdx.x;
  int base = bbase[b];
  int cnt = bbase[b + 1] - base;
  for (int i = tid; i < BN; i += 256) lh[i] = 0;
  __syncthreads();
  for (int i = tid; i < cnt; i += 256) {
    uint2 r = part[base + i];
    if (i < CAP) stage[i] = r;
    atomicAdd(&lh[r.x >> 24], 1);
  }
  __syncthreads();
  int v = (tid < BN) ? lh[tid] : 0;
  s[tid] = v;
  __syncthreads();
#pragma unroll
  for (int off = 1; off < 256; off <<= 1) {
    int u = (tid >= off) ? s[tid - off] : 0;
    __syncthreads();
    s[tid] += u;
    __syncthreads();
  }
  int ex = s[tid] - v;  // exclusive node offset within bucket
  if (tid < BN) {
    lh[tid] = ex;  // becomes running cursor
    rowptr[b * BN + tid] = base + ex;
  }
  if (b == 0 && tid == 0) rowptr[n] = E;
  __syncthreads();
  for (int i = tid; i < cnt; i += 256) {
    uint2 r = (i < CAP) ? stage[i] : part[base + i];
    int dlow = r.x >> 24;
    unsigned srcv = r.x & 0x00FFFFFFu;
    float w = __uint_as_float(r.y) * dis[srcv];
    int p = atomicAdd(&lh[dlow], 1);
    uint2 o;
    o.x = srcv;
    o.y = __float_as_uint(w);
    csr[base + p] = o;
  }
}

// ---------------- per-layer: GEMM via MFMA bf16 (layers 1,2) ----------------

__global__ __launch_bounds__(256) void k_gemm(const unsigned short* __restrict__ Zb,
                                              const unsigned short* __restrict__ Wt,
                                              unsigned short* __restrict__ H, int n) {
  int lane = threadIdx.x & 63;
  int wid  = threadIdx.x >> 6;
  int row0 = blockIdx.x * 16;
  int r  = lane & 15;
  int kg = lane >> 4;
  int c0 = wid * 32;
  const size_t abase  = (size_t)(row0 + r) * 128 + kg * 8;
  const size_t b0base = (size_t)(c0 + r) * 128 + kg * 8;
  const size_t b1base = (size_t)(c0 + 16 + r) * 128 + kg * 8;
  f32x4 acc0 = {0.f, 0.f, 0.f, 0.f};
  f32x4 acc1 = {0.f, 0.f, 0.f, 0.f};
#pragma unroll
  for (int k0 = 0; k0 < 128; k0 += 32) {
    bf16x8 a  = *(const bf16x8*)&Zb[abase + k0];
    bf16x8 b0 = *(const bf16x8*)&Wt[b0base + k0];
    bf16x8 b1 = *(const bf16x8*)&Wt[b1base + k0];
    acc0 = __builtin_amdgcn_mfma_f32_16x16x32_bf16(a, b0, acc0, 0, 0, 0);
    acc1 = __builtin_amdgcn_mfma_f32_16x16x32_bf16(a, b1, acc1, 0, 0, 0);
  }
  int orow = row0 + kg * 4;
#pragma unroll
  for (int j = 0; j < 4; ++j) {
    H[(size_t)(orow + j) * 128 + c0 + r]      = (unsigned short)bf16r(acc0[j]);
    H[(size_t)(orow + j) * 128 + c0 + 16 + r] = (unsigned short)bf16r(acc1[j]);
  }
}

// ---------------- per-layer: aggregation + bias + relu ----------------
// R14's proven gather shape: one wave per node, lane = 1 dword (2 bf16
// feats), 64 lanes = full 256B row per gather instruction; 8-edge unroll,
// dual fma chains. w = dis[src]*ew pre-folded in csr (vs R14: one fewer
// dependent load per edge).

__global__ __launch_bounds__(256) void k_agg(const unsigned* __restrict__ Hb, const int* __restrict__ rowptr,
                                             const f2v* __restrict__ csr, const float* __restrict__ dis,
                                             const float* __restrict__ bias, unsigned* __restrict__ outb,
                                             float* __restrict__ outf, int n) {
  int node = __builtin_amdgcn_readfirstlane(blockIdx.x * 4 + (threadIdx.x >> 6));
  if (node >= n) return;
  int lane = threadIdx.x & 63;
  float ax0 = 0.f, ay0 = 0.f, ax1 = 0.f, ay1 = 0.f;
  int e = rowptr[node];
  const int end = rowptr[node + 1];
  for (; e + 8 <= end; e += 8) {
    f2v r0 = __builtin_nontemporal_load(&csr[e]);
    f2v r1 = __builtin_nontemporal_load(&csr[e + 1]);
    f2v r2 = __builtin_nontemporal_load(&csr[e + 2]);
    f2v r3 = __builtin_nontemporal_load(&csr[e + 3]);
    f2v r4 = __builtin_nontemporal_load(&csr[e + 4]);
    f2v r5 = __builtin_nontemporal_load(&csr[e + 5]);
    f2v r6 = __builtin_nontemporal_load(&csr[e + 6]);
    f2v r7 = __builtin_nontemporal_load(&csr[e + 7]);
    unsigned g0 = Hb[(size_t)__float_as_int(r0.x) * 64 + lane];
    unsigned g1 = Hb[(size_t)__float_as_int(r1.x) * 64 + lane];
    unsigned g2 = Hb[(size_t)__float_as_int(r2.x) * 64 + lane];
    unsigned g3 = Hb[(size_t)__float_as_int(r3.x) * 64 + lane];
    unsigned g4 = Hb[(size_t)__float_as_int(r4.x) * 64 + lane];
    unsigned g5 = Hb[(size_t)__float_as_int(r5.x) * 64 + lane];
    unsigned g6 = Hb[(size_t)__float_as_int(r6.x) * 64 + lane];
    unsigned g7 = Hb[(size_t)__float_as_int(r7.x) * 64 + lane];
    ax0 = fmaf(__uint_as_float(g0 << 16), r0.y, ax0); ay0 = fmaf(__uint_as_float(g0 & 0xffff0000u), r0.y, ay0);
    ax1 = fmaf(__uint_as_float(g1 << 16), r1.y, ax1); ay1 = fmaf(__uint_as_float(g1 & 0xffff0000u), r1.y, ay1);
    ax0 = fmaf(__uint_as_float(g2 << 16), r2.y, ax0); ay0 = fmaf(__uint_as_float(g2 & 0xffff0000u), r2.y, ay0);
    ax1 = fmaf(__uint_as_float(g3 << 16), r3.y, ax1); ay1 = fmaf(__uint_as_float(g3 & 0xffff0000u), r3.y, ay1);
    ax0 = fmaf(__uint_as_float(g4 << 16), r4.y, ax0); ay0 = fmaf(__uint_as_float(g4 & 0xffff0000u), r4.y, ay0);
    ax1 = fmaf(__uint_as_float(g5 << 16), r5.y, ax1); ay1 = fmaf(__uint_as_float(g5 & 0xffff0000u), r5.y, ay1);
    ax0 = fmaf(__uint_as_float(g6 << 16), r6.y, ax0); ay0 = fmaf(__uint_as_float(g6 & 0xffff0000u), r6.y, ay0);
    ax1 = fmaf(__uint_as_float(g7 << 16), r7.y, ax1); ay1 = fmaf(__uint_as_float(g7 & 0xffff0000u), r7.y, ay1);
  }
  for (; e + 4 <= end; e += 4) {
    f2v r0 = __builtin_nontemporal_load(&csr[e]);
    f2v r1 = __builtin_nontemporal_load(&csr[e + 1]);
    f2v r2 = __builtin_nontemporal_load(&csr[e + 2]);
    f2v r3 = __builtin_nontemporal_load(&csr[e + 3]);
    unsigned g0 = Hb[(size_t)__float_as_int(r0.x) * 64 + lane];
    unsigned g1 = Hb[(size_t)__float_as_int(r1.x) * 64 + lane];
    unsigned g2 = Hb[(size_t)__float_as_int(r2.x) * 64 + lane];
    unsigned g3 = Hb[(size_t)__float_as_int(r3.x) * 64 + lane];
    ax0 = fmaf(__uint_as_float(g0 << 16), r0.y, ax0); ay0 = fmaf(__uint_as_float(g0 & 0xffff0000u), r0.y, ay0);
    ax1 = fmaf(__uint_as_float(g1 << 16), r1.y, ax1); ay1 = fmaf(__uint_as_float(g1 & 0xffff0000u), r1.y, ay1);
    ax0 = fmaf(__uint_as_float(g2 << 16), r2.y, ax0); ay0 = fmaf(__uint_as_float(g2 & 0xffff0000u), r2.y, ay0);
    ax1 = fmaf(__uint_as_float(g3 << 16), r3.y, ax1); ay1 = fmaf(__uint_as_float(g3 & 0xffff0000u), r3.y, ay1);
  }
  for (; e < end; ++e) {
    f2v r0 = __builtin_nontemporal_load(&csr[e]);
    unsigned g0 = Hb[(size_t)__float_as_int(r0.x) * 64 + lane];
    ax0 = fmaf(__uint_as_float(g0 << 16), r0.y, ax0); ay0 = fmaf(__uint_as_float(g0 & 0xffff0000u), r0.y, ay0);
  }
  float ax = ax0 + ax1, ay = ay0 + ay1;
  float dn = dis[node];
  float sn = dn * dn;
  unsigned hv = Hb[(size_t)node * 64 + lane];
  float hvx = __uint_as_float(hv << 16);
  float hvy = __uint_as_float(hv & 0xffff0000u);
  float2 bv = ((const float2*)bias)[lane];
  float ox = fmaxf(fmaf(dn, ax, fmaf(sn, hvx, bv.x)), 0.f);
  float oy = fmaxf(fmaf(dn, ay, fmaf(sn, hvy, bv.y)), 0.f);
  if (outb) {
    outb[(size_t)node * 64 + lane] = bf16r(ox) | (bf16r(oy) << 16);
  } else {
    f2v o; o.x = ox; o.y = oy;
    __builtin_nontemporal_store(o, (f2v*)outf + (size_t)node * 64 + lane);
  }
}

// ---------------- host ----------------

extern "C" void kernel_launch(void* const* d_in, const int* in_sizes, int n_in,
                              void* d_out, int out_size, void* d_ws, size_t ws_size,
                              hipStream_t stream) {
  const float* x  = (const float*)d_in[0];
  const int*   ei = (const int*)d_in[1];   // int32: [2, E] row-major
  const float* ew = (const float*)d_in[2];
  const float* W0 = (const float*)d_in[3];
  const float* W1 = (const float*)d_in[5];
  const float* W2 = (const float*)d_in[7];
  const float* bl[3] = {(const float*)d_in[4], (const float*)d_in[6], (const float*)d_in[8]};

  const int n = in_sizes[0] / D;   // 50000 == NB*BN
  const int E = in_sizes[1] / 2;
  const int* src = ei;
  const int* dst = ei + E;

  char* p = (char*)d_ws;
  unsigned short* Zb     = (unsigned short*)p; p += (size_t)n * D * 2;  // xb for layer 0
  unsigned short* H      = (unsigned short*)p; p += (size_t)n * D * 2;
  float*          dis    = (float*)p;          p += (size_t)n * 4;
  int*            rowptr = (int*)p;            p += (size_t)(n + 1) * 4;
  int*            M      = (int*)p;            p += (size_t)NB * NBLK * 4;
  int*            bbase  = (int*)p;            p += (size_t)(NB + 1) * 4;
  int*            bsum2  = (int*)p;            p += 512 * 4;
  int*            boff2  = (int*)p;            p += 512 * 4;
  uint2*          part   = (uint2*)p;          p += (size_t)E * 8;
  uint2*          csr    = (uint2*)p;          p += (size_t)E * 8;
  unsigned short* Wt     = (unsigned short*)p; p += 3 * 16384 * 2;
  (void)ws_size; (void)n_in;

  const int total4 = n * D / 4;            // 1.6M
  const int GC = (total4 + 255) / 256;     // 6250
  const int GW = (3 * 16384 + 255) / 256;  // 192
  const int GG = n / 16;                   // 3125 (n % 16 == 0)
  const int flatN = NB * NBLK;             // 128000
  const int GS = flatN / 256;              // 500

  k_pre1<<<NBLK + GC + GW, 256, 0, stream>>>(dst, M, E, x, Zb, total4, GC, W0, W1, W2, Wt);
  k_blocksum<<<GS, 256, 0, stream>>>(M, bsum2, flatN);
  k_scanb2<<<1, 512, 0, stream>>>(bsum2, boff2, GS);
  k_scanm<<<GS, 256, 0, stream>>>(M, boff2, bbase, flatN, E);
  k_pre2<<<GG + NBLK, 256, 0, stream>>>(Zb, Wt, H, n, GG, src, dst, ew, M, part, E);
  k_deg<<<NB, 256, 0, stream>>>(part, bbase, dis, n);
  k_bsort<<<NB, 256, 0, stream>>>(part, bbase, dis, csr, rowptr, n, E);

  float* outp = (float*)d_out;
  // layer 0 aggregation (gemm0 already done inside k_pre2)
  k_agg<<<(n + 3) / 4, 256, 0, stream>>>((const unsigned*)H, rowptr, (const f2v*)csr, dis, bl[0], (unsigned*)Zb, outp, n);
  for (int l = 1; l < 3; ++l) {
    k_gemm<<<GG, 256, 0, stream>>>(Zb, Wt + l * 16384, H, n);
    unsigned* ob = (l == 2) ? nullptr : (unsigned*)Zb;
    k_agg<<<(n + 3) / 4, 256, 0, stream>>>((const unsigned*)H, rowptr, (const f2v*)csr, dis, bl[l], ob, outp, n);
  }
}